// Round 1
// baseline (1253.822 us; speedup 1.0000x reference)
//
#include <hip/hip_runtime.h>
#include <math.h>

#define NROWS 524288
#define CHUNK 16
#define NCHUNK (NROWS / CHUNK)   // 32768
#define GRID 4096                // 8 chunks per block

__device__ __forceinline__ float gelu_exact(float x) {
    // jax.nn.gelu(approximate=False) = 0.5*x*(1+erf(x/sqrt(2)))
    return 0.5f * x * (1.0f + erff(x * 0.70710678118654752440f));
}

__global__ __launch_bounds__(256, 3)
void encoder_kernel(const int* __restrict__ read_count,
                    const int* __restrict__ write_count,
                    const int* __restrict__ fault_count,
                    const int* __restrict__ cow_count,
                    const int* __restrict__ recency,
                    const float* __restrict__ volatility,
                    const float* __restrict__ pressure,
                    const float* __restrict__ count_emb,
                    const float* __restrict__ recency_emb,
                    const float* __restrict__ p_w1, const float* __restrict__ p_b1,
                    const float* __restrict__ p_w2, const float* __restrict__ p_b2,
                    const float* __restrict__ v_w1, const float* __restrict__ v_b1,
                    const float* __restrict__ v_w2, const float* __restrict__ v_b2,
                    const float* __restrict__ f_wh, const float* __restrict__ f_bh,
                    const float* __restrict__ f_wg, const float* __restrict__ f_bg,
                    const float* __restrict__ ln_g, const float* __restrict__ ln_b,
                    float* __restrict__ out)
{
    __shared__ __align__(16) float s_cemb[320];
    __shared__ __align__(16) float s_remb[320];
    __shared__ __align__(16) float s_vw1[32];
    __shared__ __align__(16) float s_vw2[48];
    __shared__ __align__(16) float s_pw1[288];
    __shared__ __align__(16) float s_pw2[480];
    __shared__ float s_vb1[8], s_vb2[8], s_pb1[24], s_pb2[20];
    __shared__ __align__(16) float s_hid[CHUNK][32];
    __shared__ __align__(16) float s_comb[CHUNK][52];   // 52*4=208 B rows, 16B-aligned
    __shared__ __align__(16) float s_z[CHUNK][256];
    __shared__ float s_mu[CHUNK], s_rs[CHUNK];

    const int tid  = threadIdx.x;
    const int lane = tid & 63;
    const int wave = tid >> 6;

    // ---- param staging (once per block) ----
    for (int i = tid; i < 320; i += 256) { s_cemb[i] = count_emb[i]; s_remb[i] = recency_emb[i]; }
    if (tid < 8)  s_vb1[tid] = v_b1[tid];
    if (tid < 6)  s_vb2[tid] = v_b2[tid];
    if (tid < 24) s_pb1[tid] = p_b1[tid];
    if (tid < 20) s_pb2[tid] = p_b2[tid];

    // ---- BitNet ternary quantization, one tensor per wave ----
    {
        const float* src; float* dst; int n;
        if (wave == 0)      { src = v_w1; dst = s_vw1; n = 32;  }
        else if (wave == 1) { src = v_w2; dst = s_vw2; n = 48;  }
        else if (wave == 2) { src = p_w1; dst = s_pw1; n = 288; }
        else                { src = p_w2; dst = s_pw2; n = 480; }
        float s = 0.0f;
        for (int i = lane; i < n; i += 64) s += fabsf(src[i]);
        #pragma unroll
        for (int off = 32; off > 0; off >>= 1) s += __shfl_xor(s, off, 64);
        const float scale = s / (float)n;       // per-tensor absmean
        const float den   = scale + 1e-5f;
        for (int i = lane; i < n; i += 64) {
            float q = rintf(src[i] / den);      // rintf = round-half-even (matches jnp.round)
            q = fminf(1.0f, fmaxf(-1.0f, q));
            dst[i] = q * scale;
        }
    }

    // ---- per-thread fused-projection weights: column `tid` of h and g ----
    float wh[51], wg[51];
    #pragma unroll
    for (int k = 0; k < 51; ++k) { wh[k] = f_wh[tid * 51 + k]; wg[k] = f_wg[tid * 51 + k]; }
    const float bh = f_bh[tid], bg = f_bg[tid];
    const float lgam = ln_g[tid], lbet = ln_b[tid];
    __syncthreads();

    for (int c = blockIdx.x; c < NCHUNK; c += GRID) {
        const long long row0 = (long long)c * CHUNK;

        // Phase A: hidden neurons for both MLPs (16 rows x 32 units)
        for (int t2 = tid; t2 < CHUNK * 32; t2 += 256) {
            const int r = t2 >> 5, u = t2 & 31;
            const long long R = row0 + r;
            float acc;
            if (u < 24) {
                acc = s_pb1[u];
                const float* w = s_pw1 + u * 12;
                const float* x = pressure + R * 12;
                #pragma unroll
                for (int k = 0; k < 12; ++k) acc = fmaf(w[k], x[k], acc);
            } else {
                const int uu = u - 24;
                acc = s_vb1[uu];
                const float* w = s_vw1 + uu * 4;
                const float* x = volatility + R * 4;
                #pragma unroll
                for (int k = 0; k < 4; ++k) acc = fmaf(w[k], x[k], acc);
            }
            s_hid[r][u] = gelu_exact(acc);
        }
        __syncthreads();

        // Phase B: assemble combined[51] per row (emb 0..24 | p_vol 25..30 | p_pres 31..50)
        for (int t2 = tid; t2 < CHUNK * 52; t2 += 256) {
            const int r = t2 / 52, sIdx = t2 - r * 52;
            const long long R = row0 + r;
            float val = 0.0f;
            if (sIdx < 25) {
                const int table = sIdx / 5, pos = sIdx - table * 5;
                int idx; const float* emb = s_cemb;
                switch (table) {
                    case 0: idx = read_count[R];  break;
                    case 1: idx = write_count[R]; break;
                    case 2: idx = fault_count[R]; break;
                    case 3: idx = cow_count[R];   break;
                    default: idx = recency[R]; emb = s_remb; break;
                }
                val = emb[idx * 5 + pos];
            } else if (sIdx < 31) {
                const int u = sIdx - 25;
                float acc = s_vb2[u];
                #pragma unroll
                for (int k = 0; k < 8; ++k) acc = fmaf(s_vw2[u * 8 + k], s_hid[r][24 + k], acc);
                val = acc;
            } else if (sIdx < 51) {
                const int u = sIdx - 31;
                float acc = s_pb2[u];
                #pragma unroll
                for (int k = 0; k < 24; ++k) acc = fmaf(s_pw2[u * 24 + k], s_hid[r][k], acc);
                val = acc;
            }
            s_comb[r][sIdx] = val;  // sIdx==51 pad
        }
        __syncthreads();

        // Phase C: fused 51->512 projection; thread owns (h[tid], g[tid])
        #pragma unroll 1
        for (int r = 0; r < CHUNK; ++r) {
            float ah = 0.0f, ag = 0.0f;
            #pragma unroll
            for (int k = 0; k < 51; ++k) {
                const float cb = s_comb[r][k];   // LDS broadcast, b128-mergeable
                ah = fmaf(cb, wh[k], ah);
                ag = fmaf(cb, wg[k], ag);
            }
            const float hv = ah + bh;
            const float gv = 1.0f / (1.0f + __expf(-(ag + bg)));
            s_z[r][tid] = gv * hv;
        }
        __syncthreads();

        // Phase D: LayerNorm stats, 16 lanes per row
        {
            const int r = tid >> 4, l = tid & 15;
            float sum = 0.0f, sq = 0.0f;
            #pragma unroll
            for (int j = 0; j < 16; ++j) {
                const float z = s_z[r][l + 16 * j];
                sum += z; sq += z * z;
            }
            #pragma unroll
            for (int off = 1; off < 16; off <<= 1) {
                sum += __shfl_xor(sum, off, 64);
                sq  += __shfl_xor(sq,  off, 64);
            }
            const float mu  = sum * (1.0f / 256.0f);
            const float var = sq * (1.0f / 256.0f) - mu * mu;
            if (l == 0) { s_mu[r] = mu; s_rs[r] = rsqrtf(var + 1e-5f); }
        }
        __syncthreads();

        // Phase E: normalize + coalesced nontemporal store
        #pragma unroll 1
        for (int r = 0; r < CHUNK; ++r) {
            const float val = (s_z[r][tid] - s_mu[r]) * s_rs[r] * lgam + lbet;
            __builtin_nontemporal_store(val, &out[(row0 + r) * 256 + tid]);
        }
        __syncthreads();
    }
}

extern "C" void kernel_launch(void* const* d_in, const int* in_sizes, int n_in,
                              void* d_out, int out_size, void* d_ws, size_t ws_size,
                              hipStream_t stream) {
    const int*   read_count  = (const int*)d_in[0];
    const int*   write_count = (const int*)d_in[1];
    const int*   fault_count = (const int*)d_in[2];
    const int*   cow_count   = (const int*)d_in[3];
    const int*   recency     = (const int*)d_in[4];
    const float* volatility  = (const float*)d_in[5];
    const float* pressure    = (const float*)d_in[6];
    const float* count_emb   = (const float*)d_in[7];
    const float* recency_emb = (const float*)d_in[8];
    const float* p_w1 = (const float*)d_in[9];
    const float* p_b1 = (const float*)d_in[10];
    const float* p_w2 = (const float*)d_in[11];
    const float* p_b2 = (const float*)d_in[12];
    const float* v_w1 = (const float*)d_in[13];
    const float* v_b1 = (const float*)d_in[14];
    const float* v_w2 = (const float*)d_in[15];
    const float* v_b2 = (const float*)d_in[16];
    const float* f_wh = (const float*)d_in[17];
    const float* f_bh = (const float*)d_in[18];
    const float* f_wg = (const float*)d_in[19];
    const float* f_bg = (const float*)d_in[20];
    const float* ln_g = (const float*)d_in[21];
    const float* ln_b = (const float*)d_in[22];
    float* out = (float*)d_out;

    encoder_kernel<<<GRID, 256, 0, stream>>>(
        read_count, write_count, fault_count, cow_count, recency,
        volatility, pressure, count_emb, recency_emb,
        p_w1, p_b1, p_w2, p_b2, v_w1, v_b1, v_w2, v_b2,
        f_wh, f_bh, f_wg, f_bg, ln_g, ln_b, out);
}